// Round 5
// baseline (2170.422 us; speedup 1.0000x reference)
//
#include <hip/hip_runtime.h>

// ---------------------------------------------------------------- constants
namespace {
constexpr int   B_   = 16;
constexpr int   N_   = 20000;
constexpr int   C_   = 64;
constexpr int   DIM_ = 128;
constexpr int   E_   = 640000;
constexpr int   NB_  = 3;
constexpr int   ROW_ = B_ * C_;      // 1024 elements per node row in [N,B,C]
constexpr int   NR_  = N_ * B_;      // 320000 rows of C elements

constexpr int   LDK2 = 152;          // LDS k-stride (bf16); 304B row stride

// SpMM phase blocking
constexpr int   PH_   = 16;          // phases
constexpr int   PCOL_ = ROW_ / PH_;  // 64 cols (128B) per phase
constexpr int   NPB_  = 16;          // nodes per block (16 lanes each)
constexpr int   NCHK_ = N_ / NPB_;   // 1250 chunks per phase
constexpr int   NBIN_ = 1024;        // degree-sort bins

// bf16 weight region sizes (elements)
constexpr int   SZ1_ = 128 * 192;    // Wc^T  per block
constexpr int   SZ2_ = 128 * 128;    // w1^T  per block
constexpr int   SZ3_ = 64 * 128;     // w2^T  per block
constexpr int   SZB_ = SZ1_ + SZ2_ + SZ3_;
constexpr int   WTOT_ = NB_ * SZB_;

// workspace layout (bytes)
constexpr size_t SZH_  = (size_t)N_ * ROW_ * sizeof(float);   // fp32 h
constexpr size_t SZHB_ = (size_t)N_ * ROW_ * 2;               // bf16 row image
constexpr size_t OFF_H    = 0;
constexpr size_t OFF_HB   = SZH_;
constexpr size_t OFF_T1B  = OFF_HB  + SZHB_;
constexpr size_t OFF_SB   = OFF_T1B + SZHB_;
constexpr size_t OFF_DEG  = OFF_SB  + SZHB_;
constexpr size_t OFF_CNT  = OFF_DEG + (size_t)N_ * 4;
constexpr size_t OFF_OFFS = OFF_CNT + (size_t)N_ * 4;
constexpr size_t OFF_CV   = ((OFF_OFFS + (size_t)(N_ + 1) * 4 + 255) / 256) * 256;
constexpr size_t OFF_PERM = OFF_CV   + (size_t)E_ * 8;
constexpr size_t OFF_HIST = OFF_PERM + (size_t)N_ * 4;
constexpr size_t OFF_HOFF = OFF_HIST + (size_t)NBIN_ * 4;
constexpr size_t OFF_HFIL = OFF_HOFF + (size_t)NBIN_ * 4;
constexpr size_t OFF_WTC  = OFF_HFIL + (size_t)NBIN_ * 4;
constexpr size_t OFF_WT1  = OFF_WTC + (size_t)NB_ * SZ1_ * 2;
constexpr size_t OFF_WT2  = OFF_WT1 + (size_t)NB_ * SZ2_ * 2;
// total ~210 MB
} // namespace

typedef short s16x8 __attribute__((ext_vector_type(8)));
typedef float f32x4 __attribute__((ext_vector_type(4)));
typedef unsigned int u32;

__device__ __forceinline__ u32 bfr(float x) {
    u32 u = __float_as_uint(x);
    return (u + 0x7FFFu + ((u >> 16) & 1u)) >> 16;
}
__device__ __forceinline__ u32 pack_bf2(float x, float y) {
    return bfr(x) | (bfr(y) << 16);
}
__device__ __forceinline__ float bflo(u32 u) { return __uint_as_float(u << 16); }
__device__ __forceinline__ float bfhi(u32 u) { return __uint_as_float(u & 0xFFFF0000u); }

// ---------------------------------------------------------------- graph prep
__global__ void deg_cnt_k(const int* __restrict__ src, const int* __restrict__ dst,
                          const float* __restrict__ ew,
                          float* __restrict__ deg, int* __restrict__ cnt) {
    int e = blockIdx.x * 256 + threadIdx.x;
    if (e < E_) {
        atomicAdd(deg + src[e], ew[e]);
        atomicAdd(cnt + dst[e], 1);
    }
}

__global__ void dinv_k(float* __restrict__ deg) {
    int i = blockIdx.x * 256 + threadIdx.x;
    if (i < N_) {
        float d = deg[i];
        deg[i] = (d > 0.f) ? rsqrtf(fmaxf(d, 1e-12f)) : 0.f;
    }
}

__global__ __launch_bounds__(1024) void scan_k(const int* __restrict__ cnt,
                                               int* __restrict__ offs) {
    __shared__ int sums[1024];
    const int tid = threadIdx.x;
    constexpr int CH = (N_ + 1023) / 1024;   // 20
    const int base = tid * CH;
    int local = 0;
    for (int j = 0; j < CH; ++j) {
        int i = base + j;
        if (i < N_) local += cnt[i];
    }
    sums[tid] = local;
    __syncthreads();
    for (int off = 1; off < 1024; off <<= 1) {
        int v = sums[tid];
        int u = (tid >= off) ? sums[tid - off] : 0;
        __syncthreads();
        sums[tid] = v + u;
        __syncthreads();
    }
    int run = (tid > 0) ? sums[tid - 1] : 0;
    for (int j = 0; j < CH; ++j) {
        int i = base + j;
        if (i < N_) { offs[i] = run; run += cnt[i]; }
    }
    if (tid == 1023) offs[N_] = sums[1023];
}

// degree histogram / scan / perm-scatter (degree-sorted node order)
__global__ void hist_k(const int* __restrict__ cnt, int* __restrict__ hist) {
    int i = blockIdx.x * 256 + threadIdx.x;
    if (i < N_) atomicAdd(hist + min(cnt[i], NBIN_ - 1), 1);
}

__global__ __launch_bounds__(1024) void hscan_k(const int* __restrict__ hist,
                                                int* __restrict__ hoffs) {
    __shared__ int s[NBIN_];
    int t = threadIdx.x;
    s[t] = hist[t];
    __syncthreads();
    for (int off = 1; off < NBIN_; off <<= 1) {
        int v = s[t];
        int u = (t >= off) ? s[t - off] : 0;
        __syncthreads();
        s[t] = v + u;
        __syncthreads();
    }
    hoffs[t] = (t > 0) ? s[t - 1] : 0;
}

__global__ void permscatter_k(const int* __restrict__ cnt, const int* __restrict__ hoffs,
                              int* __restrict__ hfill, int* __restrict__ perm) {
    int i = blockIdx.x * 256 + threadIdx.x;
    if (i < N_) {
        int b = min(cnt[i], NBIN_ - 1);
        int pos = hoffs[b] + atomicAdd(hfill + b, 1);
        perm[pos] = i;
    }
}

__global__ void scatter_k(const int* __restrict__ src, const int* __restrict__ dst,
                          const float* __restrict__ ew, const float* __restrict__ dinv,
                          const int* __restrict__ offs, int* __restrict__ fill,
                          int2* __restrict__ cv) {
    int e = blockIdx.x * 256 + threadIdx.x;
    if (e < E_) {
        int s = src[e], d = dst[e];
        int pos = offs[d] + atomicAdd(fill + d, 1);
        float w = -dinv[s] * ew[e] * dinv[d];
        cv[pos] = make_int2(s, __float_as_int(w));
    }
}

// ---------------------------------------------------------------- bf16 weight prep
__global__ void wprep_k(const float* __restrict__ cw, const float* __restrict__ w1,
                        const float* __restrict__ w2,
                        short* __restrict__ wtc, short* __restrict__ wt1,
                        short* __restrict__ wt2) {
    int idx = blockIdx.x * 256 + threadIdx.x;
    if (idx >= WTOT_) return;
    int b = idx / SZB_;
    int rem = idx - b * SZB_;
    if (rem < SZ1_) {
        int n = rem / 192, k = rem - n * 192;
        int part = k >> 6, c = k & 63;
        const float* base = cw + (size_t)b * 3 * 64 * 128;
        float v;
        if (part == 0)      v = base[c * 128 + n] - base[16384 + c * 128 + n];
        else if (part == 1) v = base[8192 + c * 128 + n];
        else                v = 2.f * base[16384 + c * 128 + n];
        wtc[(size_t)b * SZ1_ + n * 192 + k] = (short)bfr(v);
    } else if (rem < SZ1_ + SZ2_) {
        int r2 = rem - SZ1_;
        int n = r2 >> 7, k = r2 & 127;
        float v = w1[(size_t)b * 16384 + k * 128 + n];
        wt1[(size_t)b * SZ2_ + n * 128 + k] = (short)bfr(v);
    } else {
        int r3 = rem - SZ1_ - SZ2_;
        int n = r3 >> 7, k = r3 & 127;
        float v = w2[(size_t)b * 8192 + k * 64 + n];
        wt2[(size_t)b * SZ3_ + n * 128 + k] = (short)bfr(v);
    }
}

// ---------------------------------------------------------------- transposes
__global__ void transpose_in_k(const float* __restrict__ x, float* __restrict__ h,
                               ushort* __restrict__ hb) {
    int idx = blockIdx.x * 256 + threadIdx.x;
    int c4 = idx & 15;
    int nb = idx >> 4;        // n*B + b
    int b  = nb & (B_ - 1);
    int n  = nb >> 4;
    const float4 v = *(const float4*)(x + ((size_t)b * N_ + n) * C_ + (c4 << 2));
    *(float4*)(h + (size_t)nb * C_ + (c4 << 2)) = v;
    uint2 p;
    p.x = pack_bf2(v.x, v.y);
    p.y = pack_bf2(v.z, v.w);
    *(uint2*)(hb + (size_t)nb * C_ + (c4 << 2)) = p;
}

__global__ void transpose_out_k(const float* __restrict__ h, float* __restrict__ out) {
    int idx = blockIdx.x * 256 + threadIdx.x;
    int c4 = idx & 15;
    int nb = idx >> 4;
    int b  = nb & (B_ - 1);
    int n  = nb >> 4;
    const float4 v = *(const float4*)(h + (size_t)nb * C_ + (c4 << 2));
    *(float4*)(out + ((size_t)b * N_ + n) * C_ + (c4 << 2)) = v;
}

// ---------------------------------------------------------------- SpMM, phase-blocked
// grid = PH_*NCHK_ blocks (phase-major). Block: 16 nodes x 16 lanes; lane owns 8B
// of the node's 128B phase-slice. Per phase the gather working set is N*128B =
// 2.56 MB -> XCD-L2 resident. Nodes processed in degree-sorted order (perm).
__global__ __launch_bounds__(256) void spmm_ph_k(const ushort* __restrict__ in,
                                                 ushort* __restrict__ out,
                                                 const int* __restrict__ offs,
                                                 const int2* __restrict__ cv,
                                                 const int* __restrict__ perm) {
    const int blk = blockIdx.x;
    const int ph  = blk / NCHK_;
    const int chunk = blk - ph * NCHK_;
    const int g      = threadIdx.x >> 4;
    const int lane16 = threadIdx.x & 15;
    const int n = perm[chunk * NPB_ + g];
    const int s0 = offs[n], s1 = offs[n + 1];
    const size_t coff = (size_t)ph * PCOL_ + (lane16 << 2);

    float a0 = 0.f, a1 = 0.f, a2 = 0.f, a3 = 0.f;
    int i = s0;
    for (; i + 3 < s1; i += 4) {
        int2 e0 = cv[i], e1 = cv[i + 1], e2 = cv[i + 2], e3 = cv[i + 3];
        uint2 v0 = *(const uint2*)(in + (size_t)e0.x * ROW_ + coff);
        uint2 v1 = *(const uint2*)(in + (size_t)e1.x * ROW_ + coff);
        uint2 v2 = *(const uint2*)(in + (size_t)e2.x * ROW_ + coff);
        uint2 v3 = *(const uint2*)(in + (size_t)e3.x * ROW_ + coff);
        float w0 = __int_as_float(e0.y), w1 = __int_as_float(e1.y);
        float w2 = __int_as_float(e2.y), w3 = __int_as_float(e3.y);
        a0 += w0 * bflo(v0.x) + w1 * bflo(v1.x) + w2 * bflo(v2.x) + w3 * bflo(v3.x);
        a1 += w0 * bfhi(v0.x) + w1 * bfhi(v1.x) + w2 * bfhi(v2.x) + w3 * bfhi(v3.x);
        a2 += w0 * bflo(v0.y) + w1 * bflo(v1.y) + w2 * bflo(v2.y) + w3 * bflo(v3.y);
        a3 += w0 * bfhi(v0.y) + w1 * bfhi(v1.y) + w2 * bfhi(v2.y) + w3 * bfhi(v3.y);
    }
    for (; i < s1; ++i) {
        int2 e0 = cv[i];
        uint2 v0 = *(const uint2*)(in + (size_t)e0.x * ROW_ + coff);
        float w0 = __int_as_float(e0.y);
        a0 += w0 * bflo(v0.x);
        a1 += w0 * bfhi(v0.x);
        a2 += w0 * bflo(v0.y);
        a3 += w0 * bfhi(v0.y);
    }
    uint2 p;
    p.x = pack_bf2(a0, a1);
    p.y = pack_bf2(a2, a3);
    *(uint2*)(out + (size_t)n * ROW_ + coff) = p;
}

// ---------------------------------------------------------------- MFMA MLP block
// WG = 256 thr = 4 waves, 64 rows (16 rows/wave). Single shared g-buffer:
// stage-2 reads all of g (as g1) before its epilogue writes (as g2); per-wave
// DS ops execute in order and rows are wave-private, so aliasing is safe.
// LDS 19456B -> 8 blocks/CU.
__global__ __launch_bounds__(256, 8) void mlp_mfma_k(
        float* __restrict__ h, ushort* __restrict__ hb,
        const ushort* __restrict__ t1b, const ushort* __restrict__ sb,
        const short* __restrict__ wtc, const short* __restrict__ wt1,
        const short* __restrict__ wt2,
        const float* __restrict__ cbias, const float* __restrict__ b1,
        const float* __restrict__ b2, const float* __restrict__ betap) {
    __shared__ short gbuf[64 * LDK2];

    const int tid  = threadIdx.x;
    const int wv   = tid >> 6;
    const int lane = tid & 63;
    const int m    = lane & 15;
    const int q    = lane >> 4;
    const int row0 = blockIdx.x * 64;
    const int rloc = wv << 4;
    const size_t growA = (size_t)(row0 + rloc + m);
    const float sp    = __logf(1.f + __expf(betap[0]));
    const float inv11 = 1.0f / 1.1f;

    // ---- stage 1: [t0|t1|s](192) @ Wc^T -> 128, swish -> gbuf
    f32x4 acc[8];
#pragma unroll
    for (int t = 0; t < 8; ++t) acc[t] = (f32x4){0.f, 0.f, 0.f, 0.f};
    const ushort* srcs[3] = { hb, t1b, sb };
#pragma unroll
    for (int kb = 0; kb < 6; ++kb) {
        const ushort* ap = srcs[kb >> 1] + growA * C_ + ((kb & 1) << 5) + (q << 3);
        s16x8 af = *(const s16x8*)ap;
#pragma unroll
        for (int t = 0; t < 8; ++t) {
            s16x8 bf = *(const s16x8*)(wtc + ((t << 4) + m) * 192 + (kb << 5) + (q << 3));
            acc[t] = __builtin_amdgcn_mfma_f32_16x16x32_bf16(af, bf, acc[t], 0, 0, 0);
        }
    }
#pragma unroll
    for (int t = 0; t < 8; ++t) {
        float bv = cbias[(t << 4) + m];
#pragma unroll
        for (int r = 0; r < 4; ++r) {
            float o = acc[t][r] + bv;
            float g = o * (1.f / (1.f + __expf(-o * sp))) * inv11;
            gbuf[(rloc + (q << 2) + r) * LDK2 + (t << 4) + m] = (short)bfr(g);
        }
    }

    // ---- stage 2: g1(128) @ w1^T -> 128, swish -> gbuf (aliased, in-order safe)
    f32x4 acc2[8];
#pragma unroll
    for (int t = 0; t < 8; ++t) acc2[t] = (f32x4){0.f, 0.f, 0.f, 0.f};
#pragma unroll
    for (int k0 = 0; k0 < 128; k0 += 32) {
        s16x8 af = *(const s16x8*)&gbuf[(rloc + m) * LDK2 + k0 + (q << 3)];
#pragma unroll
        for (int t = 0; t < 8; ++t) {
            s16x8 bf = *(const s16x8*)(wt1 + (((t << 4) + m) << 7) + k0 + (q << 3));
            acc2[t] = __builtin_amdgcn_mfma_f32_16x16x32_bf16(af, bf, acc2[t], 0, 0, 0);
        }
    }
#pragma unroll
    for (int t = 0; t < 8; ++t) {
        float bv = b1[(t << 4) + m];
#pragma unroll
        for (int r = 0; r < 4; ++r) {
            float o = acc2[t][r] + bv;
            float g = o * (1.f / (1.f + __expf(-o * sp))) * inv11;
            gbuf[(rloc + (q << 2) + r) * LDK2 + (t << 4) + m] = (short)bfr(g);
        }
    }

    // ---- stage 3: g2(128) @ w2^T -> 64, h += f (residual fused), refresh hb
    f32x4 acc3[4];
#pragma unroll
    for (int t = 0; t < 4; ++t) acc3[t] = (f32x4){0.f, 0.f, 0.f, 0.f};
#pragma unroll
    for (int k0 = 0; k0 < 128; k0 += 32) {
        s16x8 af = *(const s16x8*)&gbuf[(rloc + m) * LDK2 + k0 + (q << 3)];
#pragma unroll
        for (int t = 0; t < 4; ++t) {
            s16x8 bf = *(const s16x8*)(wt2 + (((t << 4) + m) << 7) + k0 + (q << 3));
            acc3[t] = __builtin_amdgcn_mfma_f32_16x16x32_bf16(af, bf, acc3[t], 0, 0, 0);
        }
    }
#pragma unroll
    for (int t = 0; t < 4; ++t) {
        float bv = b2[(t << 4) + m];
#pragma unroll
        for (int r = 0; r < 4; ++r) {
            size_t eidx = (size_t)(row0 + rloc + (q << 2) + r) * C_ + (t << 4) + m;
            float nv = h[eidx] + acc3[t][r] + bv;
            h[eidx] = nv;
            hb[eidx] = (ushort)bfr(nv);
        }
    }
}

// ---------------------------------------------------------------- launch
extern "C" void kernel_launch(void* const* d_in, const int* in_sizes, int n_in,
                              void* d_out, int out_size, void* d_ws, size_t ws_size,
                              hipStream_t stream) {
    const float* x    = (const float*)d_in[0];
    const int*   ei   = (const int*)d_in[1];
    const float* ew   = (const float*)d_in[2];
    const float* cw   = (const float*)d_in[3];
    const float* cb   = (const float*)d_in[4];
    const float* beta = (const float*)d_in[5];
    const float* w1   = (const float*)d_in[6];
    const float* b1   = (const float*)d_in[7];
    const float* w2   = (const float*)d_in[8];
    const float* b2   = (const float*)d_in[9];
    float* out = (float*)d_out;

    char* ws = (char*)d_ws;
    float*  h_t  = (float*) (ws + OFF_H);
    ushort* hb   = (ushort*)(ws + OFF_HB);
    ushort* t1b  = (ushort*)(ws + OFF_T1B);
    ushort* sb   = (ushort*)(ws + OFF_SB);
    float*  deg  = (float*) (ws + OFF_DEG);
    int*    cnt  = (int*)   (ws + OFF_CNT);
    int*    offs = (int*)   (ws + OFF_OFFS);
    int2*   cv   = (int2*)  (ws + OFF_CV);
    int*    perm = (int*)   (ws + OFF_PERM);
    int*    hist = (int*)   (ws + OFF_HIST);
    int*    hoff = (int*)   (ws + OFF_HOFF);
    int*    hfil = (int*)   (ws + OFF_HFIL);
    short*  wtc  = (short*) (ws + OFF_WTC);
    short*  wt1  = (short*) (ws + OFF_WT1);
    short*  wt2  = (short*) (ws + OFF_WT2);

    const int* srcI = ei;
    const int* dstI = ei + E_;

    // graph prep
    hipMemsetAsync(deg, 0, (size_t)N_ * 4, stream);
    hipMemsetAsync(cnt, 0, (size_t)N_ * 4, stream);
    hipMemsetAsync(hist, 0, (size_t)NBIN_ * 4, stream);
    hipMemsetAsync(hfil, 0, (size_t)NBIN_ * 4, stream);
    deg_cnt_k<<<(E_ + 255) / 256, 256, 0, stream>>>(srcI, dstI, ew, deg, cnt);
    dinv_k<<<(N_ + 255) / 256, 256, 0, stream>>>(deg);
    scan_k<<<1, 1024, 0, stream>>>(cnt, offs);
    hist_k<<<(N_ + 255) / 256, 256, 0, stream>>>(cnt, hist);
    hscan_k<<<1, NBIN_, 0, stream>>>(hist, hoff);
    permscatter_k<<<(N_ + 255) / 256, 256, 0, stream>>>(cnt, hoff, hfil, perm);
    hipMemsetAsync(cnt, 0, (size_t)N_ * 4, stream);
    scatter_k<<<(E_ + 255) / 256, 256, 0, stream>>>(srcI, dstI, ew, deg, offs, cnt, cv);

    // bf16 weights
    wprep_k<<<(WTOT_ + 255) / 256, 256, 0, stream>>>(cw, w1, w2, wtc, wt1, wt2);

    // x -> [N,B,C] (fp32 + bf16 image)
    transpose_in_k<<<(N_ * B_ * 16) / 256, 256, 0, stream>>>(x, h_t, hb);

    for (int b = 0; b < NB_; ++b) {
        spmm_ph_k<<<PH_ * NCHK_, 256, 0, stream>>>(hb, t1b, offs, cv, perm);
        spmm_ph_k<<<PH_ * NCHK_, 256, 0, stream>>>(t1b, sb, offs, cv, perm);
        mlp_mfma_k<<<NR_ / 64, 256, 0, stream>>>(h_t, hb, t1b, sb,
                                                 wtc + (size_t)b * SZ1_,
                                                 wt1 + (size_t)b * SZ2_,
                                                 wt2 + (size_t)b * SZ3_,
                                                 cb + (size_t)b * DIM_,
                                                 b1 + (size_t)b * DIM_,
                                                 b2 + (size_t)b * C_,
                                                 beta + b);
    }

    // [N,B,C] -> out
    transpose_out_k<<<(N_ * B_ * 16) / 256, 256, 0, stream>>>(h_t, out);
}

// Round 6
// 1967.205 us; speedup vs baseline: 1.1033x; 1.1033x over previous
//
#include <hip/hip_runtime.h>

// ---------------------------------------------------------------- constants
namespace {
constexpr int   B_   = 16;
constexpr int   N_   = 20000;
constexpr int   C_   = 64;
constexpr int   DIM_ = 128;
constexpr int   E_   = 640000;
constexpr int   NB_  = 3;
constexpr int   ROW_ = B_ * C_;      // 1024 elements per node row in [N,B,C]
constexpr int   NR_  = N_ * B_;      // 320000 rows of C elements

constexpr int   LDK2 = 152;          // LDS k-stride (bf16); 304B row stride

// SpMM phase blocking
constexpr int   PH_   = 16;          // phases
constexpr int   PCOL_ = ROW_ / PH_;  // 64 cols (128B) per phase
constexpr int   NPB_  = 16;          // nodes per block (16 lanes each)
constexpr int   NCHK_ = N_ / NPB_;   // 1250 chunks per phase
constexpr int   NBIN_ = 1024;        // degree-sort bins

// bf16 weight region sizes (elements)
constexpr int   SZ1_ = 128 * 192;    // Wc^T  per block
constexpr int   SZ2_ = 128 * 128;    // w1^T  per block
constexpr int   SZ3_ = 64 * 128;     // w2^T  per block
constexpr int   SZB_ = SZ1_ + SZ2_ + SZ3_;
constexpr int   WTOT_ = NB_ * SZB_;

// workspace layout (bytes)
constexpr size_t SZH_  = (size_t)N_ * ROW_ * sizeof(float);   // fp32 h
constexpr size_t SZHB_ = (size_t)N_ * ROW_ * 2;               // bf16 row image
constexpr size_t OFF_H    = 0;
constexpr size_t OFF_HB   = SZH_;
constexpr size_t OFF_T1B  = OFF_HB  + SZHB_;
constexpr size_t OFF_SB   = OFF_T1B + SZHB_;
constexpr size_t OFF_DEG  = OFF_SB  + SZHB_;
constexpr size_t OFF_CNT  = OFF_DEG + (size_t)N_ * 4;
constexpr size_t OFF_OFFS = OFF_CNT + (size_t)N_ * 4;
constexpr size_t OFF_CV   = ((OFF_OFFS + (size_t)(N_ + 1) * 4 + 255) / 256) * 256;
constexpr size_t OFF_PERM = OFF_CV   + (size_t)E_ * 8;
constexpr size_t OFF_HIST = OFF_PERM + (size_t)N_ * 4;
constexpr size_t OFF_HOFF = OFF_HIST + (size_t)NBIN_ * 4;
constexpr size_t OFF_HFIL = OFF_HOFF + (size_t)NBIN_ * 4;
constexpr size_t OFF_WTC  = OFF_HFIL + (size_t)NBIN_ * 4;
constexpr size_t OFF_WT1  = OFF_WTC + (size_t)NB_ * SZ1_ * 2;
constexpr size_t OFF_WT2  = OFF_WT1 + (size_t)NB_ * SZ2_ * 2;
// total ~210 MB
} // namespace

typedef short s16x8 __attribute__((ext_vector_type(8)));
typedef float f32x4 __attribute__((ext_vector_type(4)));
typedef unsigned int u32;

__device__ __forceinline__ u32 bfr(float x) {
    u32 u = __float_as_uint(x);
    return (u + 0x7FFFu + ((u >> 16) & 1u)) >> 16;
}
__device__ __forceinline__ u32 pack_bf2(float x, float y) {
    return bfr(x) | (bfr(y) << 16);
}
__device__ __forceinline__ float bflo(u32 u) { return __uint_as_float(u << 16); }
__device__ __forceinline__ float bfhi(u32 u) { return __uint_as_float(u & 0xFFFF0000u); }

// ---------------------------------------------------------------- graph prep
__global__ void deg_cnt_k(const int* __restrict__ src, const int* __restrict__ dst,
                          const float* __restrict__ ew,
                          float* __restrict__ deg, int* __restrict__ cnt) {
    int e = blockIdx.x * 256 + threadIdx.x;
    if (e < E_) {
        atomicAdd(deg + src[e], ew[e]);
        atomicAdd(cnt + dst[e], 1);
    }
}

__global__ void dinv_k(float* __restrict__ deg) {
    int i = blockIdx.x * 256 + threadIdx.x;
    if (i < N_) {
        float d = deg[i];
        deg[i] = (d > 0.f) ? rsqrtf(fmaxf(d, 1e-12f)) : 0.f;
    }
}

__global__ __launch_bounds__(1024) void scan_k(const int* __restrict__ cnt,
                                               int* __restrict__ offs) {
    __shared__ int sums[1024];
    const int tid = threadIdx.x;
    constexpr int CH = (N_ + 1023) / 1024;   // 20
    const int base = tid * CH;
    int local = 0;
    for (int j = 0; j < CH; ++j) {
        int i = base + j;
        if (i < N_) local += cnt[i];
    }
    sums[tid] = local;
    __syncthreads();
    for (int off = 1; off < 1024; off <<= 1) {
        int v = sums[tid];
        int u = (tid >= off) ? sums[tid - off] : 0;
        __syncthreads();
        sums[tid] = v + u;
        __syncthreads();
    }
    int run = (tid > 0) ? sums[tid - 1] : 0;
    for (int j = 0; j < CH; ++j) {
        int i = base + j;
        if (i < N_) { offs[i] = run; run += cnt[i]; }
    }
    if (tid == 1023) offs[N_] = sums[1023];
}

// degree histogram / scan / perm-scatter (degree-sorted node order)
__global__ void hist_k(const int* __restrict__ cnt, int* __restrict__ hist) {
    int i = blockIdx.x * 256 + threadIdx.x;
    if (i < N_) atomicAdd(hist + min(cnt[i], NBIN_ - 1), 1);
}

__global__ __launch_bounds__(1024) void hscan_k(const int* __restrict__ hist,
                                                int* __restrict__ hoffs) {
    __shared__ int s[NBIN_];
    int t = threadIdx.x;
    s[t] = hist[t];
    __syncthreads();
    for (int off = 1; off < NBIN_; off <<= 1) {
        int v = s[t];
        int u = (t >= off) ? s[t - off] : 0;
        __syncthreads();
        s[t] = v + u;
        __syncthreads();
    }
    hoffs[t] = (t > 0) ? s[t - 1] : 0;
}

__global__ void permscatter_k(const int* __restrict__ cnt, const int* __restrict__ hoffs,
                              int* __restrict__ hfill, int* __restrict__ perm) {
    int i = blockIdx.x * 256 + threadIdx.x;
    if (i < N_) {
        int b = min(cnt[i], NBIN_ - 1);
        int pos = hoffs[b] + atomicAdd(hfill + b, 1);
        perm[pos] = i;
    }
}

__global__ void scatter_k(const int* __restrict__ src, const int* __restrict__ dst,
                          const float* __restrict__ ew, const float* __restrict__ dinv,
                          const int* __restrict__ offs, int* __restrict__ fill,
                          int2* __restrict__ cv) {
    int e = blockIdx.x * 256 + threadIdx.x;
    if (e < E_) {
        int s = src[e], d = dst[e];
        int pos = offs[d] + atomicAdd(fill + d, 1);
        float w = -dinv[s] * ew[e] * dinv[d];
        cv[pos] = make_int2(s, __float_as_int(w));
    }
}

// ---------------------------------------------------------------- bf16 weight prep
__global__ void wprep_k(const float* __restrict__ cw, const float* __restrict__ w1,
                        const float* __restrict__ w2,
                        short* __restrict__ wtc, short* __restrict__ wt1,
                        short* __restrict__ wt2) {
    int idx = blockIdx.x * 256 + threadIdx.x;
    if (idx >= WTOT_) return;
    int b = idx / SZB_;
    int rem = idx - b * SZB_;
    if (rem < SZ1_) {
        int n = rem / 192, k = rem - n * 192;
        int part = k >> 6, c = k & 63;
        const float* base = cw + (size_t)b * 3 * 64 * 128;
        float v;
        if (part == 0)      v = base[c * 128 + n] - base[16384 + c * 128 + n];
        else if (part == 1) v = base[8192 + c * 128 + n];
        else                v = 2.f * base[16384 + c * 128 + n];
        wtc[(size_t)b * SZ1_ + n * 192 + k] = (short)bfr(v);
    } else if (rem < SZ1_ + SZ2_) {
        int r2 = rem - SZ1_;
        int n = r2 >> 7, k = r2 & 127;
        float v = w1[(size_t)b * 16384 + k * 128 + n];
        wt1[(size_t)b * SZ2_ + n * 128 + k] = (short)bfr(v);
    } else {
        int r3 = rem - SZ1_ - SZ2_;
        int n = r3 >> 7, k = r3 & 127;
        float v = w2[(size_t)b * 8192 + k * 64 + n];
        wt2[(size_t)b * SZ3_ + n * 128 + k] = (short)bfr(v);
    }
}

// ---------------------------------------------------------------- transposes
__global__ void transpose_in_k(const float* __restrict__ x, float* __restrict__ h,
                               ushort* __restrict__ hb) {
    int idx = blockIdx.x * 256 + threadIdx.x;
    int c4 = idx & 15;
    int nb = idx >> 4;        // n*B + b
    int b  = nb & (B_ - 1);
    int n  = nb >> 4;
    const float4 v = *(const float4*)(x + ((size_t)b * N_ + n) * C_ + (c4 << 2));
    *(float4*)(h + (size_t)nb * C_ + (c4 << 2)) = v;
    uint2 p;
    p.x = pack_bf2(v.x, v.y);
    p.y = pack_bf2(v.z, v.w);
    *(uint2*)(hb + (size_t)nb * C_ + (c4 << 2)) = p;
}

__global__ void transpose_out_k(const float* __restrict__ h, float* __restrict__ out) {
    int idx = blockIdx.x * 256 + threadIdx.x;
    int c4 = idx & 15;
    int nb = idx >> 4;
    int b  = nb & (B_ - 1);
    int n  = nb >> 4;
    const float4 v = *(const float4*)(h + (size_t)nb * C_ + (c4 << 2));
    *(float4*)(out + ((size_t)b * N_ + n) * C_ + (c4 << 2)) = v;
}

// ---------------------------------------------------------------- SpMM, phase-blocked
// grid = PH_*NCHK_ blocks (phase-major). Block: 16 nodes x 16 lanes; lane owns 8B
// of the node's 128B phase-slice. Per phase the gather working set is N*128B =
// 2.56 MB -> XCD-L2 resident. Nodes processed in degree-sorted order (perm).
__global__ __launch_bounds__(256) void spmm_ph_k(const ushort* __restrict__ in,
                                                 ushort* __restrict__ out,
                                                 const int* __restrict__ offs,
                                                 const int2* __restrict__ cv,
                                                 const int* __restrict__ perm) {
    const int blk = blockIdx.x;
    const int ph  = blk / NCHK_;
    const int chunk = blk - ph * NCHK_;
    const int g      = threadIdx.x >> 4;
    const int lane16 = threadIdx.x & 15;
    const int n = perm[chunk * NPB_ + g];
    const int s0 = offs[n], s1 = offs[n + 1];
    const size_t coff = (size_t)ph * PCOL_ + (lane16 << 2);

    float a0 = 0.f, a1 = 0.f, a2 = 0.f, a3 = 0.f;
    int i = s0;
    for (; i + 3 < s1; i += 4) {
        int2 e0 = cv[i], e1 = cv[i + 1], e2 = cv[i + 2], e3 = cv[i + 3];
        uint2 v0 = *(const uint2*)(in + (size_t)e0.x * ROW_ + coff);
        uint2 v1 = *(const uint2*)(in + (size_t)e1.x * ROW_ + coff);
        uint2 v2 = *(const uint2*)(in + (size_t)e2.x * ROW_ + coff);
        uint2 v3 = *(const uint2*)(in + (size_t)e3.x * ROW_ + coff);
        float w0 = __int_as_float(e0.y), w1 = __int_as_float(e1.y);
        float w2 = __int_as_float(e2.y), w3 = __int_as_float(e3.y);
        a0 += w0 * bflo(v0.x) + w1 * bflo(v1.x) + w2 * bflo(v2.x) + w3 * bflo(v3.x);
        a1 += w0 * bfhi(v0.x) + w1 * bfhi(v1.x) + w2 * bfhi(v2.x) + w3 * bfhi(v3.x);
        a2 += w0 * bflo(v0.y) + w1 * bflo(v1.y) + w2 * bflo(v2.y) + w3 * bflo(v3.y);
        a3 += w0 * bfhi(v0.y) + w1 * bfhi(v1.y) + w2 * bfhi(v2.y) + w3 * bfhi(v3.y);
    }
    for (; i < s1; ++i) {
        int2 e0 = cv[i];
        uint2 v0 = *(const uint2*)(in + (size_t)e0.x * ROW_ + coff);
        float w0 = __int_as_float(e0.y);
        a0 += w0 * bflo(v0.x);
        a1 += w0 * bfhi(v0.x);
        a2 += w0 * bflo(v0.y);
        a3 += w0 * bfhi(v0.y);
    }
    uint2 p;
    p.x = pack_bf2(a0, a1);
    p.y = pack_bf2(a2, a3);
    *(uint2*)(out + (size_t)n * ROW_ + coff) = p;
}

// ---------------------------------------------------------------- MFMA MLP block
// WG = 256 thr = 4 waves, 64 rows (16 rows/wave). Single shared g-buffer:
// stage-2 reads all of g (as g1) before its epilogue writes (as g2); per-wave
// DS ops execute in order and rows are wave-private, so aliasing is safe.
// LDS 19456B -> 8 blocks/CU. launch_bounds kept at (256,4): forcing 8 waves/EU
// clamped the allocator to 32 VGPR and spilled ~300MB/dispatch to scratch (r5).
__global__ __launch_bounds__(256, 4) void mlp_mfma_k(
        float* __restrict__ h, ushort* __restrict__ hb,
        const ushort* __restrict__ t1b, const ushort* __restrict__ sb,
        const short* __restrict__ wtc, const short* __restrict__ wt1,
        const short* __restrict__ wt2,
        const float* __restrict__ cbias, const float* __restrict__ b1,
        const float* __restrict__ b2, const float* __restrict__ betap) {
    __shared__ short gbuf[64 * LDK2];

    const int tid  = threadIdx.x;
    const int wv   = tid >> 6;
    const int lane = tid & 63;
    const int m    = lane & 15;
    const int q    = lane >> 4;
    const int row0 = blockIdx.x * 64;
    const int rloc = wv << 4;
    const size_t growA = (size_t)(row0 + rloc + m);
    const float sp    = __logf(1.f + __expf(betap[0]));
    const float inv11 = 1.0f / 1.1f;

    // ---- stage 1: [t0|t1|s](192) @ Wc^T -> 128, swish -> gbuf
    f32x4 acc[8];
#pragma unroll
    for (int t = 0; t < 8; ++t) acc[t] = (f32x4){0.f, 0.f, 0.f, 0.f};
    const ushort* srcs[3] = { hb, t1b, sb };
#pragma unroll
    for (int kb = 0; kb < 6; ++kb) {
        const ushort* ap = srcs[kb >> 1] + growA * C_ + ((kb & 1) << 5) + (q << 3);
        s16x8 af = *(const s16x8*)ap;
#pragma unroll
        for (int t = 0; t < 8; ++t) {
            s16x8 bf = *(const s16x8*)(wtc + ((t << 4) + m) * 192 + (kb << 5) + (q << 3));
            acc[t] = __builtin_amdgcn_mfma_f32_16x16x32_bf16(af, bf, acc[t], 0, 0, 0);
        }
    }
#pragma unroll
    for (int t = 0; t < 8; ++t) {
        float bv = cbias[(t << 4) + m];
#pragma unroll
        for (int r = 0; r < 4; ++r) {
            float o = acc[t][r] + bv;
            float g = o * (1.f / (1.f + __expf(-o * sp))) * inv11;
            gbuf[(rloc + (q << 2) + r) * LDK2 + (t << 4) + m] = (short)bfr(g);
        }
    }

    // ---- stage 2: g1(128) @ w1^T -> 128, swish -> gbuf (aliased, in-order safe)
    f32x4 acc2[8];
#pragma unroll
    for (int t = 0; t < 8; ++t) acc2[t] = (f32x4){0.f, 0.f, 0.f, 0.f};
#pragma unroll
    for (int k0 = 0; k0 < 128; k0 += 32) {
        s16x8 af = *(const s16x8*)&gbuf[(rloc + m) * LDK2 + k0 + (q << 3)];
#pragma unroll
        for (int t = 0; t < 8; ++t) {
            s16x8 bf = *(const s16x8*)(wt1 + (((t << 4) + m) << 7) + k0 + (q << 3));
            acc2[t] = __builtin_amdgcn_mfma_f32_16x16x32_bf16(af, bf, acc2[t], 0, 0, 0);
        }
    }
#pragma unroll
    for (int t = 0; t < 8; ++t) {
        float bv = b1[(t << 4) + m];
#pragma unroll
        for (int r = 0; r < 4; ++r) {
            float o = acc2[t][r] + bv;
            float g = o * (1.f / (1.f + __expf(-o * sp))) * inv11;
            gbuf[(rloc + (q << 2) + r) * LDK2 + (t << 4) + m] = (short)bfr(g);
        }
    }

    // ---- stage 3: g2(128) @ w2^T -> 64, h += f (residual fused), refresh hb
    f32x4 acc3[4];
#pragma unroll
    for (int t = 0; t < 4; ++t) acc3[t] = (f32x4){0.f, 0.f, 0.f, 0.f};
#pragma unroll
    for (int k0 = 0; k0 < 128; k0 += 32) {
        s16x8 af = *(const s16x8*)&gbuf[(rloc + m) * LDK2 + k0 + (q << 3)];
#pragma unroll
        for (int t = 0; t < 4; ++t) {
            s16x8 bf = *(const s16x8*)(wt2 + (((t << 4) + m) << 7) + k0 + (q << 3));
            acc3[t] = __builtin_amdgcn_mfma_f32_16x16x32_bf16(af, bf, acc3[t], 0, 0, 0);
        }
    }
#pragma unroll
    for (int t = 0; t < 4; ++t) {
        float bv = b2[(t << 4) + m];
#pragma unroll
        for (int r = 0; r < 4; ++r) {
            size_t eidx = (size_t)(row0 + rloc + (q << 2) + r) * C_ + (t << 4) + m;
            float nv = h[eidx] + acc3[t][r] + bv;
            h[eidx] = nv;
            hb[eidx] = (ushort)bfr(nv);
        }
    }
}

// ---------------------------------------------------------------- launch
extern "C" void kernel_launch(void* const* d_in, const int* in_sizes, int n_in,
                              void* d_out, int out_size, void* d_ws, size_t ws_size,
                              hipStream_t stream) {
    const float* x    = (const float*)d_in[0];
    const int*   ei   = (const int*)d_in[1];
    const float* ew   = (const float*)d_in[2];
    const float* cw   = (const float*)d_in[3];
    const float* cb   = (const float*)d_in[4];
    const float* beta = (const float*)d_in[5];
    const float* w1   = (const float*)d_in[6];
    const float* b1   = (const float*)d_in[7];
    const float* w2   = (const float*)d_in[8];
    const float* b2   = (const float*)d_in[9];
    float* out = (float*)d_out;

    char* ws = (char*)d_ws;
    float*  h_t  = (float*) (ws + OFF_H);
    ushort* hb   = (ushort*)(ws + OFF_HB);
    ushort* t1b  = (ushort*)(ws + OFF_T1B);
    ushort* sb   = (ushort*)(ws + OFF_SB);
    float*  deg  = (float*) (ws + OFF_DEG);
    int*    cnt  = (int*)   (ws + OFF_CNT);
    int*    offs = (int*)   (ws + OFF_OFFS);
    int2*   cv   = (int2*)  (ws + OFF_CV);
    int*    perm = (int*)   (ws + OFF_PERM);
    int*    hist = (int*)   (ws + OFF_HIST);
    int*    hoff = (int*)   (ws + OFF_HOFF);
    int*    hfil = (int*)   (ws + OFF_HFIL);
    short*  wtc  = (short*) (ws + OFF_WTC);
    short*  wt1  = (short*) (ws + OFF_WT1);
    short*  wt2  = (short*) (ws + OFF_WT2);

    const int* srcI = ei;
    const int* dstI = ei + E_;

    // graph prep
    hipMemsetAsync(deg, 0, (size_t)N_ * 4, stream);
    hipMemsetAsync(cnt, 0, (size_t)N_ * 4, stream);
    hipMemsetAsync(hist, 0, (size_t)NBIN_ * 4, stream);
    hipMemsetAsync(hfil, 0, (size_t)NBIN_ * 4, stream);
    deg_cnt_k<<<(E_ + 255) / 256, 256, 0, stream>>>(srcI, dstI, ew, deg, cnt);
    dinv_k<<<(N_ + 255) / 256, 256, 0, stream>>>(deg);
    scan_k<<<1, 1024, 0, stream>>>(cnt, offs);
    hist_k<<<(N_ + 255) / 256, 256, 0, stream>>>(cnt, hist);
    hscan_k<<<1, NBIN_, 0, stream>>>(hist, hoff);
    permscatter_k<<<(N_ + 255) / 256, 256, 0, stream>>>(cnt, hoff, hfil, perm);
    hipMemsetAsync(cnt, 0, (size_t)N_ * 4, stream);
    scatter_k<<<(E_ + 255) / 256, 256, 0, stream>>>(srcI, dstI, ew, deg, offs, cnt, cv);

    // bf16 weights
    wprep_k<<<(WTOT_ + 255) / 256, 256, 0, stream>>>(cw, w1, w2, wtc, wt1, wt2);

    // x -> [N,B,C] (fp32 + bf16 image)
    transpose_in_k<<<(N_ * B_ * 16) / 256, 256, 0, stream>>>(x, h_t, hb);

    for (int b = 0; b < NB_; ++b) {
        spmm_ph_k<<<PH_ * NCHK_, 256, 0, stream>>>(hb, t1b, offs, cv, perm);
        spmm_ph_k<<<PH_ * NCHK_, 256, 0, stream>>>(t1b, sb, offs, cv, perm);
        mlp_mfma_k<<<NR_ / 64, 256, 0, stream>>>(h_t, hb, t1b, sb,
                                                 wtc + (size_t)b * SZ1_,
                                                 wt1 + (size_t)b * SZ2_,
                                                 wt2 + (size_t)b * SZ3_,
                                                 cb + (size_t)b * DIM_,
                                                 b1 + (size_t)b * DIM_,
                                                 b2 + (size_t)b * C_,
                                                 beta + b);
    }

    // [N,B,C] -> out
    transpose_out_k<<<(N_ * B_ * 16) / 256, 256, 0, stream>>>(h_t, out);
}